// Round 4
// baseline (378.284 us; speedup 1.0000x reference)
//
#include <hip/hip_runtime.h>

#define B_    2
#define CE_   32
#define D_    12
#define H_    256
#define W_    256
#define HW_   (H_*W_)
#define HID_  256
#define NPD   8
#define NPH   25
#define NPW   25
#define NP_   10000
#define PJ    1805               // 5*19*19
#define NTILE 113                // ceil(1805/16)
#define JS_   16                 // j-splits
#define MB_   157                // ceil(10000/64) m-blocks (64 slots each)
#define NSLOT (MB_*64)           // 10048 padded slots
#define NMT   (MB_*4)            // 628 padded m-tiles

typedef __attribute__((ext_vector_type(8))) short s8v;     // 8 bf16
typedef __attribute__((ext_vector_type(4))) float f32x4;

__device__ __forceinline__ unsigned short f2bf(float f) {
    unsigned u = __float_as_uint(f);
    u += 0x7FFFu + ((u >> 16) & 1u);   // RNE
    return (unsigned short)(u >> 16);
}

// ---- blocks 0..112: W2[k][j] -> W2t[j][k] bf16 rows; block 113: (offj,bj) LUT
__global__ __launch_bounds__(256) void k_pre(
    const float* __restrict__ W2, const float* __restrict__ b2,
    unsigned short* __restrict__ W2t, int2* __restrict__ lut)
{
    const int t = threadIdx.x;
    if (blockIdx.x < 113) {
        __shared__ unsigned short tile[16][264];
        const int j0 = blockIdx.x * 16;
        const int jj = t & 15, kb = t >> 4;
        #pragma unroll
        for (int ki = 0; ki < 16; ki++) {
            const int k = kb*16 + ki;
            const int j = j0 + jj;
            const float v = (j < PJ) ? W2[(size_t)k*PJ + j] : 0.f;
            tile[jj][k] = f2bf(v);
        }
        __syncthreads();
        const int jr = t >> 4, kc = t & 15;
        s8v a = *(const s8v*)&tile[jr][kc*16];
        s8v b = *(const s8v*)&tile[jr][kc*16+8];
        *(s8v*)&W2t[(size_t)(j0+jr)*HID_ + kc*16]     = a;
        *(s8v*)&W2t[(size_t)(j0+jr)*HID_ + kc*16 + 8] = b;
    } else {
        for (int i = t; i < NTILE*16; i += 256) {
            int off = 0; float bj = 0.f;
            if (i < PJ) {
                const int dz = i/361, rj = i - dz*361;
                const int yy = rj/19, xx = rj - yy*19;
                off = dz*HW_ + yy*(2*W_) + xx*2;
                bj = b2[i];
            }
            lut[i] = make_int2(off, __float_as_int(bj));
        }
    }
}

// ---- packed 2x2 min/max of gt: M[bd][h][w] = (min<<8)|max
__global__ __launch_bounds__(256) void k_mm(
    const float* __restrict__ target, unsigned short* __restrict__ M)
{
    __shared__ float rows[5][256];
    const int t  = threadIdx.x;
    const int bd = blockIdx.x >> 6;          // b*D+d
    const int h0 = (blockIdx.x & 63) << 2;
    const int b  = bd / D_, d = bd - b*D_;
    const size_t gbase = ((size_t)(b*4*D_) + d)*HW_;
    #pragma unroll
    for (int r = 0; r < 5; r++) {
        int h = h0 + r; if (h > 255) h = 255;
        rows[r][t] = target[gbase + h*W_ + t];
    }
    __syncthreads();
    const int w1 = (t < 255) ? t+1 : 255;
    #pragma unroll
    for (int r = 0; r < 4; r++) {
        const float g00 = rows[r][t],   g01 = rows[r][w1];
        const float g10 = rows[r+1][t], g11 = rows[r+1][w1];
        const float mn = fminf(fminf(g00,g01), fminf(g10,g11));
        const float mx = fmaxf(fmaxf(g00,g01), fmaxf(g10,g11));
        M[(size_t)bd*HW_ + (h0+r)*W_ + t] = (unsigned short)(((int)mn << 8) | (int)mx);
    }
}

// ---- emb gather + GEMM1(+ReLU) -> compacted bf16 A-frags + slot metadata
__global__ __launch_bounds__(256) void k_prep(
    const float* __restrict__ target, const float* __restrict__ pred,
    const float* __restrict__ W1, const float* __restrict__ b1,
    unsigned short* __restrict__ hA, unsigned* __restrict__ cp,
    int* __restrict__ mbase, int* __restrict__ val, int* __restrict__ cnt)
{
    __shared__ float emb_s[8][CE_];
    __shared__ int slot_s[8];
    const int tid = threadIdx.x;
    const int n0  = blockIdx.x * 8;
    const int m   = tid & 7;
    const int c   = tid >> 3;
    {
        const int n = n0 + m;
        const int b = n / (NPD*NPH*NPW);
        const int r = n - b*(NPD*NPH*NPW);
        const int pd = r/(NPH*NPW); const int r2 = r - pd*(NPH*NPW);
        const int ph = r2/NPW, pw = r2 - ph*NPW;
        const int dc = 2+pd, hc = 21+9*ph, wc = 21+9*pw;
        emb_s[m][c] = pred[(((size_t)b*CE_ + c)*D_ + dc)*HW_ + (size_t)hc*W_ + wc];
        if (c == 0) {
            const size_t tb = ((size_t)(b*4)*D_ + dc)*HW_ + (size_t)hc*W_ + wc;
            const float ctr = target[tb];
            const float a1 = target[tb + (size_t)(1*D_*HW_)];
            const float a2 = target[tb + (size_t)(2*D_*HW_)];
            const float a3 = target[tb + (size_t)(3*D_*HW_)];
            const bool v = (ctr!=0.f) && (a1!=0.f) && (a2!=0.f) && (a3!=0.f);
            int s = -1;
            if (v) {
                s = atomicAdd(cnt, 1);
                const int ci = (int)ctr;
                cp[s]    = (unsigned)((ci<<8)|ci);
                mbase[s] = (b*D_+pd)*HW_ + (2+9*ph)*W_ + (2+9*pw);
                val[s]   = 1;
            }
            slot_s[m] = s;
        }
    }
    __syncthreads();
    float acc[8];
    const float bb = b1[tid];
    #pragma unroll
    for (int mm = 0; mm < 8; mm++) acc[mm] = bb;
    #pragma unroll
    for (int ccc = 0; ccc < CE_; ccc += 4) {
        const float w0 = W1[(size_t)(ccc+0)*HID_ + tid];
        const float w1v = W1[(size_t)(ccc+1)*HID_ + tid];
        const float w2v = W1[(size_t)(ccc+2)*HID_ + tid];
        const float w3 = W1[(size_t)(ccc+3)*HID_ + tid];
        #pragma unroll
        for (int mm = 0; mm < 8; mm++) {
            const float4 e = *(const float4*)&emb_s[mm][ccc];
            float a = acc[mm];
            a = fmaf(e.x, w0, a);
            a = fmaf(e.y, w1v, a);
            a = fmaf(e.z, w2v, a);
            a = fmaf(e.w, w3, a);
            acc[mm] = a;
        }
    }
    // write h into A-fragment order at compacted slot
    const int kk = tid>>5, quad=(tid>>3)&3, e=tid&7;
    #pragma unroll
    for (int mm = 0; mm < 8; mm++) {
        const int s = slot_s[mm];
        if (s >= 0) {
            const int mt = s>>4, l16 = s&15;
            hA[(size_t)((mt*8+kk)*4+quad)*128 + l16*8 + e] = f2bf(fmaxf(acc[mm],0.f));
        }
    }
}

// ---- MFMA GEMM2 + sigmoid + mask + reduce (compacted slots)
__global__ __launch_bounds__(256, 4) void k_main(
    const unsigned short* __restrict__ hA, const unsigned short* __restrict__ W2t,
    const int2* __restrict__ lut, const unsigned short* __restrict__ M,
    const unsigned* __restrict__ cp, const int* __restrict__ mbase,
    const int* __restrict__ val, const int* __restrict__ cnt,
    double* __restrict__ accs)
{
    __shared__ unsigned short Bf[2][16*264];   // row stride 264 ushorts (528 B)
    __shared__ float red_s[4][3];

    const int m0 = blockIdx.x * 64;
    if (m0 >= *cnt) return;                    // whole-block uniform early exit

    const int tid  = threadIdx.x;
    const int mt   = tid >> 6;
    const int lane = tid & 63;
    const int quad = lane >> 4;
    const int l16  = lane & 15;
    const int js   = blockIdx.y;
    const int t0   = (NTILE*js)/JS_, t1 = (NTILE*(js+1))/JS_;
    const int mtile = (m0 >> 4) + mt;

    // A fragments (global, frag-order, contiguous 16B/lane)
    s8v afr[8];
    #pragma unroll
    for (int kk = 0; kk < 8; kk++)
        afr[kk] = *(const s8v*)&hA[(size_t)((mtile*8+kk)*4+quad)*128 + l16*8];

    int vv[4]; unsigned cpv[4]; int mbv[4];
    #pragma unroll
    for (int r = 0; r < 4; r++) {
        const int p = mtile*16 + quad*4 + r;
        vv[r] = val[p]; cpv[r] = cp[p]; mbv[r] = mbase[p];
    }

    // stage first B tile: thread (jj = tid>>4, cc = tid&15) moves 2x16B
    const int jj = tid >> 4, ccs = tid & 15;
    {
        const unsigned short* src = W2t + (size_t)(t0*16+jj)*HID_ + ccs*8;
        s8v a = *(const s8v*)src;
        s8v b = *(const s8v*)(src + 128);
        *(s8v*)&Bf[0][jj*264 + ccs*8]       = a;
        *(s8v*)&Bf[0][jj*264 + 128 + ccs*8] = b;
    }
    __syncthreads();

    float num = 0.f, denp = 0.f, dent = 0.f;
    for (int tt = t0; tt < t1; tt++) {
        const int cur = (tt - t0) & 1;
        s8v pa, pb;
        const bool have = (tt+1 < t1);
        if (have) {
            const unsigned short* src = W2t + (size_t)((tt+1)*16+jj)*HID_ + ccs*8;
            pa = *(const s8v*)src;
            pb = *(const s8v*)(src + 128);
        }
        // GEMM2 on current buffer
        const unsigned short* bb = &Bf[cur][0];
        f32x4 acc = {0.f,0.f,0.f,0.f};
        #pragma unroll
        for (int kk = 0; kk < 8; kk++) {
            const s8v bfr = *(const s8v*)&bb[l16*264 + kk*32 + quad*8];
            acc = __builtin_amdgcn_mfma_f32_16x16x32_bf16(afr[kk], bfr, acc, 0, 0, 0);
        }
        // epilogue
        const int j = tt*16 + l16;
        const int2 lb = lut[j];
        const int offj = lb.x;
        const float bj = __int_as_float(lb.y);
        const bool jok = (j < PJ);
        #pragma unroll
        for (int r = 0; r < 4; r++) {
            if (jok && vv[r]) {
                const unsigned mmv = M[mbv[r] + offj];
                if (mmv >= 256u) {                 // min>0 => not ignored
                    const float tv = (mmv != cpv[r]) ? 1.f : 0.f;
                    const float pv = 1.f / (1.f + __expf(-(acc[r] + bj)));
                    num  = fmaf(pv, tv, num);
                    denp = fmaf(pv, pv, denp);
                    dent += tv;                    // t^2 == t
                }
            }
        }
        if (have) {
            *(s8v*)&Bf[cur^1][jj*264 + ccs*8]       = pa;
            *(s8v*)&Bf[cur^1][jj*264 + 128 + ccs*8] = pb;
        }
        __syncthreads();
    }

    // reduce
    #pragma unroll
    for (int off = 32; off > 0; off >>= 1) {
        num  += __shfl_down(num,  off);
        denp += __shfl_down(denp, off);
        dent += __shfl_down(dent, off);
    }
    if (lane == 0) { red_s[mt][0] = num; red_s[mt][1] = denp; red_s[mt][2] = dent; }
    __syncthreads();
    if (tid == 0) {
        const float n_ = red_s[0][0]+red_s[1][0]+red_s[2][0]+red_s[3][0];
        const float p_ = red_s[0][1]+red_s[1][1]+red_s[2][1]+red_s[3][1];
        const float t_ = red_s[0][2]+red_s[1][2]+red_s[2][2]+red_s[3][2];
        atomicAdd(&accs[0], (double)n_);
        atomicAdd(&accs[1], (double)p_);
        atomicAdd(&accs[2], (double)t_);
    }
}

__global__ void k_final(const double* __restrict__ accs, float* __restrict__ out) {
    const double num = accs[0];
    const double den = accs[1] + accs[2];
    const double d   = den > 1e-6 ? den : 1e-6;
    out[0] = (float)(-2.0 * num / d);
}

extern "C" void kernel_launch(void* const* d_in, const int* in_sizes, int n_in,
                              void* d_out, int out_size, void* d_ws, size_t ws_size,
                              hipStream_t stream) {
    const float* target = (const float*)d_in[0];
    const float* pred   = (const float*)d_in[1];
    const float* W1     = (const float*)d_in[2];
    const float* b1     = (const float*)d_in[3];
    const float* W2     = (const float*)d_in[4];
    const float* b2     = (const float*)d_in[5];
    float* out = (float*)d_out;

    char* ws = (char*)d_ws;
    double*         accs = (double*)ws;                     // 24 B
    int*            cnt  = (int*)(ws + 32);
    int*            val  = (int*)(ws + 64);                 // 10048*4 = 40192
    unsigned*       cp   = (unsigned*)(ws + 40256);         // 40192
    int*            mb   = (int*)(ws + 80448);              // 40192
    unsigned short* hA   = (unsigned short*)(ws + 120640);  // 628*8*4*128*2 = 5,144,576
    unsigned short* W2t  = (unsigned short*)(ws + 5265216); // 925,696
    int2*           lut  = (int2*)(ws + 6190912);           // 14,464
    unsigned short* Mx   = (unsigned short*)(ws + 6205376); // 3,145,728  (end ~9.35 MB)

    hipMemsetAsync(d_ws, 0, 40256, stream);                 // accs + cnt + val
    hipLaunchKernelGGL(k_pre,  dim3(114),       dim3(256), 0, stream, W2, b2, W2t, lut);
    hipLaunchKernelGGL(k_mm,   dim3(1536),      dim3(256), 0, stream, target, Mx);
    hipLaunchKernelGGL(k_prep, dim3(NP_/8),     dim3(256), 0, stream,
                       target, pred, W1, b1, hA, cp, mb, val, cnt);
    hipLaunchKernelGGL(k_main, dim3(MB_, JS_),  dim3(256), 0, stream,
                       hA, W2t, lut, Mx, cp, mb, val, cnt, accs);
    hipLaunchKernelGGL(k_final, dim3(1), dim3(1), 0, stream, accs, out);
}

// Round 5
// 350.708 us; speedup vs baseline: 1.0786x; 1.0786x over previous
//
#include <hip/hip_runtime.h>

#define B_    2
#define CE_   32
#define D_    12
#define H_    256
#define W_    256
#define HW_   (H_*W_)
#define HID_  256
#define NPD   8
#define NPH   25
#define NPW   25
#define NP_   10000
#define PJ    1805               // 5*19*19
#define NTILE 113                // ceil(1805/16)
#define JS_   16                 // j-splits
#define MB_   157                // ceil(10000/64) m-blocks
#define NSLOT (MB_*64)           // 10048 padded slots

typedef __attribute__((ext_vector_type(8))) short s8v;     // 8 bf16
typedef __attribute__((ext_vector_type(4))) float f32x4;

__device__ __forceinline__ unsigned short f2bf(float f) {
    unsigned u = __float_as_uint(f);
    u += 0x7FFFu + ((u >> 16) & 1u);   // RNE
    return (unsigned short)(u >> 16);
}

__device__ __forceinline__ void decompose_n(int n, int& b, int& pd, int& ph, int& pw) {
    b = n / (NPD*NPH*NPW);
    int r = n - b*(NPD*NPH*NPW);
    pd = r / (NPH*NPW);
    int r2 = r - pd*(NPH*NPW);
    ph = r2 / NPW;
    pw = r2 - ph*NPW;
}

// ---------------- fused staging kernel: 4 independent phases by blockIdx ----
// blocks [0,113): W2 -> W2t bf16 transpose     (j-tile each)
// block  113    : (offj, bj) LUT
// blocks [114,1650): 2x2 min/max pack of gt -> M
// blocks [1650,1807): emb gather + slot compaction + GEMM1 -> hA frag-order
__global__ __launch_bounds__(256) void k_stage(
    const float* __restrict__ W2, const float* __restrict__ b2,
    const float* __restrict__ target, const float* __restrict__ pred,
    const float* __restrict__ W1, const float* __restrict__ b1,
    unsigned short* __restrict__ W2t, int2* __restrict__ lut,
    unsigned short* __restrict__ M, unsigned short* __restrict__ hA,
    unsigned* __restrict__ cp, int* __restrict__ mbase, int* __restrict__ cnt)
{
    const int bx = blockIdx.x;
    const int t  = threadIdx.x;

    if (bx < 113) {
        __shared__ unsigned short tile[16][264];
        const int j0 = bx * 16;
        const int jj = t & 15, kb = t >> 4;
        #pragma unroll
        for (int ki = 0; ki < 16; ki++) {
            const int k = kb*16 + ki;
            const int j = j0 + jj;
            const float v = (j < PJ) ? W2[(size_t)k*PJ + j] : 0.f;
            tile[jj][k] = f2bf(v);
        }
        __syncthreads();
        const int jr = t >> 4, kc = t & 15;
        s8v a = *(const s8v*)&tile[jr][kc*16];
        s8v b = *(const s8v*)&tile[jr][kc*16+8];
        *(s8v*)&W2t[(size_t)(j0+jr)*HID_ + kc*16]     = a;
        *(s8v*)&W2t[(size_t)(j0+jr)*HID_ + kc*16 + 8] = b;
    } else if (bx == 113) {
        for (int i = t; i < NTILE*16; i += 256) {
            int off = 0; float bj = 0.f;
            if (i < PJ) {
                const int dz = i/361, rj = i - dz*361;
                const int yy = rj/19, xx = rj - yy*19;
                off = dz*HW_ + yy*(2*W_) + xx*2;
                bj = b2[i];
            }
            lut[i] = make_int2(off, __float_as_int(bj));
        }
    } else if (bx < 1650) {
        __shared__ float rows[5][256];
        const int bx2 = bx - 114;
        const int bd = bx2 >> 6;               // b*D+d
        const int h0 = (bx2 & 63) << 2;
        const int b  = bd / D_, d = bd - b*D_;
        const size_t gbase = ((size_t)(b*4*D_) + d)*HW_;
        #pragma unroll
        for (int r = 0; r < 5; r++) {
            int h = h0 + r; if (h > 255) h = 255;
            rows[r][t] = target[gbase + h*W_ + t];
        }
        __syncthreads();
        const int w1 = (t < 255) ? t+1 : 255;
        #pragma unroll
        for (int r = 0; r < 4; r++) {
            const float g00 = rows[r][t],   g01 = rows[r][w1];
            const float g10 = rows[r+1][t], g11 = rows[r+1][w1];
            const float mn = fminf(fminf(g00,g01), fminf(g10,g11));
            const float mx = fmaxf(fmaxf(g00,g01), fmaxf(g10,g11));
            M[(size_t)bd*HW_ + (h0+r)*W_ + t] = (unsigned short)(((int)mn << 8) | (int)mx);
        }
    } else {
        __shared__ float emb_s[64][36];        // stride 36: float4-aligned rows
        __shared__ int   slot_s[64];
        const int pb = bx - 1650;              // 0..156
        const int n0 = pb * 64;
        {   // gather: thread (m = t&63, cg = t>>6) loads 8 channels
            const int m = t & 63, cg = t >> 6;
            int n = n0 + m; if (n >= NP_) n = NP_-1;
            int b, pd, ph, pw; decompose_n(n, b, pd, ph, pw);
            const int dc = 2+pd, hc = 21+9*ph, wc = 21+9*pw;
            const size_t base = ((size_t)(b*CE_ + cg*8)*D_ + dc)*HW_ + (size_t)hc*W_ + wc;
            #pragma unroll
            for (int i = 0; i < 8; i++)
                emb_s[m][cg*8+i] = pred[base + (size_t)i*D_*HW_];
        }
        if (t < 64) {   // wave 0: validity + ballot compaction (1 atomic/block)
            int n = n0 + t; const bool inb = (n < NP_); if (!inb) n = NP_-1;
            int b, pd, ph, pw; decompose_n(n, b, pd, ph, pw);
            const int dc = 2+pd, hc = 21+9*ph, wc = 21+9*pw;
            const size_t tb = ((size_t)(b*4)*D_ + dc)*HW_ + (size_t)hc*W_ + wc;
            const float ctr = target[tb];
            const float a1 = target[tb + (size_t)(1*D_*HW_)];
            const float a2 = target[tb + (size_t)(2*D_*HW_)];
            const float a3 = target[tb + (size_t)(3*D_*HW_)];
            const bool v = inb && (ctr!=0.f) && (a1!=0.f) && (a2!=0.f) && (a3!=0.f);
            const unsigned long long bal = __ballot(v);
            int base = 0;
            if (t == 0) base = atomicAdd(cnt, __popcll(bal));
            base = __shfl(base, 0);
            int s = -1;
            if (v) {
                s = base + (int)__popcll(bal & ((1ull << t) - 1ull));
                const int ci = (int)ctr;
                cp[s]    = (unsigned)((ci<<8)|ci);
                mbase[s] = (b*D_+pd)*HW_ + (2+9*ph)*W_ + (2+9*pw);
            }
            slot_s[t] = s;
        }
        __syncthreads();
        // GEMM1: thread owns column t
        float wcol[CE_];
        #pragma unroll
        for (int i = 0; i < CE_; i++) wcol[i] = W1[(size_t)i*HID_ + t];
        const float bb = b1[t];
        const int kk = t>>5, quad = (t>>3)&3, e = t&7;
        for (int mm = 0; mm < 64; mm++) {
            const int s = slot_s[mm];          // uniform branch
            if (s < 0) continue;
            float a = bb;
            #pragma unroll
            for (int cc = 0; cc < CE_; cc += 4) {
                const float4 ev = *(const float4*)&emb_s[mm][cc];
                a = fmaf(ev.x, wcol[cc+0], a);
                a = fmaf(ev.y, wcol[cc+1], a);
                a = fmaf(ev.z, wcol[cc+2], a);
                a = fmaf(ev.w, wcol[cc+3], a);
            }
            hA[(size_t)(((s>>4)*8+kk)*4+quad)*128 + (s&15)*8 + e] = f2bf(fmaxf(a, 0.f));
        }
    }
}

// ---------------- MFMA GEMM2 + sigmoid + mask + reduce ---------------------
__global__ __launch_bounds__(256, 4) void k_main(
    const unsigned short* __restrict__ hA, const unsigned short* __restrict__ W2t,
    const int2* __restrict__ lut, const unsigned short* __restrict__ M,
    const unsigned* __restrict__ cp, const int* __restrict__ mbase,
    const int* __restrict__ cnt, double* __restrict__ accs)
{
    __shared__ unsigned short Bf[2][16*264];
    __shared__ float red_s[4][3];

    const int m0 = blockIdx.x * 64;
    const int nv = *cnt;
    if (m0 >= nv) return;                      // uniform early exit

    const int tid  = threadIdx.x;
    const int mt   = tid >> 6;
    const int lane = tid & 63;
    const int quad = lane >> 4;
    const int l16  = lane & 15;
    const int js   = blockIdx.y;
    const int t0   = (NTILE*js)/JS_, t1 = (NTILE*(js+1))/JS_;
    const int ntt  = t1 - t0;
    const int mtile = (m0 >> 4) + mt;

    // per-lane LUT slice for the whole block (kills in-loop latency chain)
    int2 lutv[8];
    #pragma unroll
    for (int i = 0; i < 8; i++) {
        int tt = t0 + i; if (tt > NTILE-1) tt = NTILE-1;
        lutv[i] = lut[tt*16 + l16];
    }

    // A fragments (frag-order, 16B/lane contiguous)
    s8v afr[8];
    #pragma unroll
    for (int kk = 0; kk < 8; kk++)
        afr[kk] = *(const s8v*)&hA[(size_t)((mtile*8+kk)*4+quad)*128 + l16*8];

    int pok[4]; unsigned cpv[4]; int mbv[4];
    #pragma unroll
    for (int r = 0; r < 4; r++) {
        const int p = mtile*16 + quad*4 + r;
        pok[r] = (p < nv);
        mbv[r] = pok[r] ? mbase[p] : 0;
        cpv[r] = pok[r] ? cp[p] : 0xFFFFFFFFu;
    }

    // stage first B tile
    const int jj = tid >> 4, ccs = tid & 15;
    {
        const unsigned short* src = W2t + (size_t)(t0*16+jj)*HID_ + ccs*8;
        s8v a = *(const s8v*)src;
        s8v b = *(const s8v*)(src + 128);
        *(s8v*)&Bf[0][jj*264 + ccs*8]       = a;
        *(s8v*)&Bf[0][jj*264 + 128 + ccs*8] = b;
    }
    __syncthreads();

    float num = 0.f, denp = 0.f, dent = 0.f;
    for (int it = 0; it < ntt; it++) {
        const int tt  = t0 + it;
        const int cur = it & 1;
        // M prefetch for THIS tile — issued before the MFMA chain
        const int offj = lutv[it].x;
        unsigned short Mv[4];
        #pragma unroll
        for (int r = 0; r < 4; r++) Mv[r] = M[mbv[r] + offj];
        // next B tile prefetch into regs
        s8v pa, pb;
        const bool have = (it+1 < ntt);
        if (have) {
            const unsigned short* src = W2t + (size_t)((tt+1)*16+jj)*HID_ + ccs*8;
            pa = *(const s8v*)src;
            pb = *(const s8v*)(src + 128);
        }
        // GEMM2 on current buffer
        const unsigned short* bb = &Bf[cur][0];
        f32x4 acc = {0.f,0.f,0.f,0.f};
        #pragma unroll
        for (int kk = 0; kk < 8; kk++) {
            const s8v bfr = *(const s8v*)&bb[l16*264 + kk*32 + quad*8];
            acc = __builtin_amdgcn_mfma_f32_16x16x32_bf16(afr[kk], bfr, acc, 0, 0, 0);
        }
        // epilogue
        const int j = tt*16 + l16;
        const bool jok = (j < PJ);
        const float bj = __int_as_float(lutv[it].y);
        #pragma unroll
        for (int r = 0; r < 4; r++) {
            if (jok && pok[r]) {
                const unsigned mmv = Mv[r];
                if (mmv >= 256u) {             // min>0 => not ignored
                    const float tv = (mmv != cpv[r]) ? 1.f : 0.f;
                    const float pv = 1.f / (1.f + __expf(-(acc[r] + bj)));
                    num  = fmaf(pv, tv, num);
                    denp = fmaf(pv, pv, denp);
                    dent += tv;                // t^2 == t
                }
            }
        }
        if (have) {
            *(s8v*)&Bf[cur^1][jj*264 + ccs*8]       = pa;
            *(s8v*)&Bf[cur^1][jj*264 + 128 + ccs*8] = pb;
        }
        __syncthreads();
    }

    // reduce
    #pragma unroll
    for (int off = 32; off > 0; off >>= 1) {
        num  += __shfl_down(num,  off);
        denp += __shfl_down(denp, off);
        dent += __shfl_down(dent, off);
    }
    if (lane == 0) { red_s[mt][0] = num; red_s[mt][1] = denp; red_s[mt][2] = dent; }
    __syncthreads();
    if (tid == 0) {
        const float n_ = red_s[0][0]+red_s[1][0]+red_s[2][0]+red_s[3][0];
        const float p_ = red_s[0][1]+red_s[1][1]+red_s[2][1]+red_s[3][1];
        const float t_ = red_s[0][2]+red_s[1][2]+red_s[2][2]+red_s[3][2];
        atomicAdd(&accs[0], (double)n_);
        atomicAdd(&accs[1], (double)p_);
        atomicAdd(&accs[2], (double)t_);
    }
}

__global__ void k_final(const double* __restrict__ accs, float* __restrict__ out) {
    const double num = accs[0];
    const double den = accs[1] + accs[2];
    const double d   = den > 1e-6 ? den : 1e-6;
    out[0] = (float)(-2.0 * num / d);
}

extern "C" void kernel_launch(void* const* d_in, const int* in_sizes, int n_in,
                              void* d_out, int out_size, void* d_ws, size_t ws_size,
                              hipStream_t stream) {
    const float* target = (const float*)d_in[0];
    const float* pred   = (const float*)d_in[1];
    const float* W1     = (const float*)d_in[2];
    const float* b1     = (const float*)d_in[3];
    const float* W2     = (const float*)d_in[4];
    const float* b2     = (const float*)d_in[5];
    float* out = (float*)d_out;

    char* ws = (char*)d_ws;
    double*         accs = (double*)ws;                       // 24 B
    int*            cnt  = (int*)(ws + 32);
    unsigned*       cp   = (unsigned*)(ws + 64);              // 10048*4 = 40192
    int*            mb   = (int*)(ws + 40256);                // 40192
    unsigned short* hA   = (unsigned short*)(ws + 80448);     // 628*8*4*128*2 = 5,144,576
    unsigned short* W2t  = (unsigned short*)(ws + 5225024);   // 925,696
    int2*           lut  = (int2*)(ws + 6150720);             // 14,464
    unsigned short* Mx   = (unsigned short*)(ws + 6165184);   // 3,145,728

    hipMemsetAsync(d_ws, 0, 64, stream);                      // accs + cnt
    hipLaunchKernelGGL(k_stage, dim3(1807),     dim3(256), 0, stream,
                       W2, b2, target, pred, W1, b1, W2t, lut, Mx, hA, cp, mb, cnt);
    hipLaunchKernelGGL(k_main,  dim3(MB_, JS_), dim3(256), 0, stream,
                       hA, W2t, lut, Mx, cp, mb, cnt, accs);
    hipLaunchKernelGGL(k_final, dim3(1), dim3(1), 0, stream, accs, out);
}

// Round 6
// 313.731 us; speedup vs baseline: 1.2058x; 1.1179x over previous
//
#include <hip/hip_runtime.h>

#define B_    2
#define CE_   32
#define D_    12
#define H_    256
#define W_    256
#define HW_   (H_*W_)
#define HID_  256
#define NPD   8
#define NPH   25
#define NPW   25
#define NP_   10000
#define PJ    1805               // 5*19*19
#define NTILE 113                // ceil(1805/16)
#define JTP   114                // padded j-tiles (even)
#define MS_   16                 // m-split (grid.y)
#define MB_   157                // ceil(10000/64)
#define NSLOT (MB_*64)           // 10048

typedef __attribute__((ext_vector_type(8))) short s8v;     // 8 bf16
typedef __attribute__((ext_vector_type(4))) float f32x4;

__device__ __forceinline__ unsigned short f2bf(float f) {
    unsigned u = __float_as_uint(f);
    u += 0x7FFFu + ((u >> 16) & 1u);   // RNE
    return (unsigned short)(u >> 16);
}

__device__ __forceinline__ void decompose_n(int n, int& b, int& pd, int& ph, int& pw) {
    b = n / (NPD*NPH*NPW);
    int r = n - b*(NPD*NPH*NPW);
    pd = r / (NPH*NPW);
    int r2 = r - pd*(NPH*NPW);
    ph = r2 / NPW;
    pw = r2 - ph*NPW;
}

// ---------------- fused staging kernel: 4 independent phases by blockIdx ----
// [0,114): W2 -> W2t bf16 transpose (rows j, padded to 1824)
// 114    : (offj, bj) LUT (1824 entries)
// [115,1651): 2x2 min/max pack of gt -> M
// [1651,1808): emb gather + ballot compaction + GEMM1 -> hA frag-order + meta
__global__ __launch_bounds__(256) void k_stage(
    const float* __restrict__ W2, const float* __restrict__ b2,
    const float* __restrict__ target, const float* __restrict__ pred,
    const float* __restrict__ W1, const float* __restrict__ b1,
    unsigned short* __restrict__ W2t, int2* __restrict__ lut,
    unsigned short* __restrict__ M, unsigned short* __restrict__ hA,
    int2* __restrict__ meta, int* __restrict__ cnt)
{
    const int bx = blockIdx.x;
    const int t  = threadIdx.x;

    if (bx < 114) {
        __shared__ unsigned short tile[16][264];
        const int j0 = bx * 16;
        const int jj = t & 15, kb = t >> 4;
        #pragma unroll
        for (int ki = 0; ki < 16; ki++) {
            const int k = kb*16 + ki;
            const int j = j0 + jj;
            const float v = (j < PJ) ? W2[(size_t)k*PJ + j] : 0.f;
            tile[jj][k] = f2bf(v);
        }
        __syncthreads();
        const int jr = t >> 4, kc = t & 15;
        s8v a = *(const s8v*)&tile[jr][kc*16];
        s8v b = *(const s8v*)&tile[jr][kc*16+8];
        *(s8v*)&W2t[(size_t)(j0+jr)*HID_ + kc*16]     = a;
        *(s8v*)&W2t[(size_t)(j0+jr)*HID_ + kc*16 + 8] = b;
    } else if (bx == 114) {
        for (int i = t; i < JTP*16; i += 256) {
            int off = 0; float bj = 0.f;
            if (i < PJ) {
                const int dz = i/361, rj = i - dz*361;
                const int yy = rj/19, xx = rj - yy*19;
                off = dz*HW_ + yy*(2*W_) + xx*2;
                bj = b2[i];
            }
            lut[i] = make_int2(off, __float_as_int(bj));
        }
    } else if (bx < 1651) {
        __shared__ float rows[5][256];
        const int bx2 = bx - 115;
        const int bd = bx2 >> 6;               // b*D+d
        const int h0 = (bx2 & 63) << 2;
        const int b  = bd / D_, d = bd - b*D_;
        const size_t gbase = ((size_t)(b*4*D_) + d)*HW_;
        #pragma unroll
        for (int r = 0; r < 5; r++) {
            int h = h0 + r; if (h > 255) h = 255;
            rows[r][t] = target[gbase + h*W_ + t];
        }
        __syncthreads();
        const int w1 = (t < 255) ? t+1 : 255;
        #pragma unroll
        for (int r = 0; r < 4; r++) {
            const float g00 = rows[r][t],   g01 = rows[r][w1];
            const float g10 = rows[r+1][t], g11 = rows[r+1][w1];
            const float mn = fminf(fminf(g00,g01), fminf(g10,g11));
            const float mx = fmaxf(fmaxf(g00,g01), fmaxf(g10,g11));
            M[(size_t)bd*HW_ + (h0+r)*W_ + t] = (unsigned short)(((int)mn << 8) | (int)mx);
        }
    } else {
        __shared__ float emb_s[64][36];        // stride 36: float4-aligned rows
        __shared__ int   slot_s[64];
        const int pb = bx - 1651;              // 0..156
        const int n0 = pb * 64;
        {   // gather: thread (m = t&63, cg = t>>6) loads 8 channels
            const int m = t & 63, cg = t >> 6;
            int n = n0 + m; if (n >= NP_) n = NP_-1;
            int b, pd, ph, pw; decompose_n(n, b, pd, ph, pw);
            const int dc = 2+pd, hc = 21+9*ph, wc = 21+9*pw;
            const size_t base = ((size_t)(b*CE_ + cg*8)*D_ + dc)*HW_ + (size_t)hc*W_ + wc;
            #pragma unroll
            for (int i = 0; i < 8; i++)
                emb_s[m][cg*8+i] = pred[base + (size_t)i*D_*HW_];
        }
        if (t < 64) {   // wave 0: validity + ballot compaction (1 atomic/block)
            int n = n0 + t; const bool inb = (n < NP_); if (!inb) n = NP_-1;
            int b, pd, ph, pw; decompose_n(n, b, pd, ph, pw);
            const int dc = 2+pd, hc = 21+9*ph, wc = 21+9*pw;
            const size_t tb = ((size_t)(b*4)*D_ + dc)*HW_ + (size_t)hc*W_ + wc;
            const float ctr = target[tb];
            const float a1 = target[tb + (size_t)(1*D_*HW_)];
            const float a2 = target[tb + (size_t)(2*D_*HW_)];
            const float a3 = target[tb + (size_t)(3*D_*HW_)];
            const bool v = inb && (ctr!=0.f) && (a1!=0.f) && (a2!=0.f) && (a3!=0.f);
            const unsigned long long bal = __ballot(v);
            int base = 0;
            if (t == 0) base = atomicAdd(cnt, __popcll(bal));
            base = __shfl(base, 0);
            int s = -1;
            if (v) {
                s = base + (int)__popcll(bal & ((1ull << t) - 1ull));
                const int ci = (int)ctr;
                meta[s] = make_int2((b*D_+pd)*HW_ + (2+9*ph)*W_ + (2+9*pw),
                                    (ci<<8)|ci);
            }
            slot_s[t] = s;
        }
        __syncthreads();
        // GEMM1: thread owns column t
        float wcol[CE_];
        #pragma unroll
        for (int i = 0; i < CE_; i++) wcol[i] = W1[(size_t)i*HID_ + t];
        const float bb = b1[t];
        const int kk = t>>5, quad = (t>>3)&3, e = t&7;
        for (int mm = 0; mm < 64; mm++) {
            const int s = slot_s[mm];          // uniform branch
            if (s < 0) continue;
            float a = bb;
            #pragma unroll
            for (int cc = 0; cc < CE_; cc += 4) {
                const float4 ev = *(const float4*)&emb_s[mm][cc];
                a = fmaf(ev.x, wcol[cc+0], a);
                a = fmaf(ev.y, wcol[cc+1], a);
                a = fmaf(ev.z, wcol[cc+2], a);
                a = fmaf(ev.w, wcol[cc+3], a);
            }
            hA[(size_t)(((s>>4)*8+kk)*4+quad)*128 + (s&15)*8 + e] = f2bf(fmaxf(a, 0.f));
        }
    }
}

// ---------------- barrier-free MFMA GEMM2 + epilogue ------------------------
// block owns 2 j-tiles (B-frags register-resident); each wave streams m-tiles
__global__ __launch_bounds__(256, 4) void k_main(
    const unsigned short* __restrict__ hA, const unsigned short* __restrict__ W2t,
    const int2* __restrict__ lut, const unsigned short* __restrict__ M,
    const int2* __restrict__ meta, const int* __restrict__ cnt,
    double* __restrict__ accs)
{
    __shared__ float red_s[4][3];
    const int tid  = threadIdx.x;
    const int wv   = tid >> 6;
    const int lane = tid & 63;
    const int quad = lane >> 4;
    const int l16  = lane & 15;
    const int jt0  = blockIdx.x * 2;       // 0..112 (jt0+1 may be pad tile 113)
    const int ms   = blockIdx.y;           // 0..MS_-1
    const int nv   = *cnt;
    const int nmt  = (nv + 15) >> 4;       // active m-tiles

    // resident B fragments for both j-tiles
    s8v bfr0[8], bfr1[8];
    {
        const unsigned short* w0 = W2t + (size_t)(jt0*16 + l16)*HID_ + quad*8;
        const unsigned short* w1 = w0 + 16*HID_;
        #pragma unroll
        for (int kk = 0; kk < 8; kk++) {
            bfr0[kk] = *(const s8v*)(w0 + kk*32);
            bfr1[kk] = *(const s8v*)(w1 + kk*32);
        }
    }
    const int j0 = jt0*16 + l16, j1 = j0 + 16;
    const int2 lb0 = lut[j0], lb1 = lut[j1];
    const bool jok0 = (j0 < PJ), jok1 = (j1 < PJ);
    const float bj0 = __int_as_float(lb0.y), bj1 = __int_as_float(lb1.y);

    float num = 0.f, denp = 0.f, dent = 0.f;

    for (int mt = ms*4 + wv; mt < nmt; mt += MS_*4) {
        const unsigned short* arow = hA + (size_t)mt*4096 + quad*128 + l16*8;
        f32x4 a0 = {0.f,0.f,0.f,0.f}, a1 = {0.f,0.f,0.f,0.f};
        #pragma unroll
        for (int kk = 0; kk < 8; kk++) {
            const s8v af = *(const s8v*)(arow + kk*512);
            a0 = __builtin_amdgcn_mfma_f32_16x16x32_bf16(af, bfr0[kk], a0, 0, 0, 0);
            a1 = __builtin_amdgcn_mfma_f32_16x16x32_bf16(af, bfr1[kk], a1, 0, 0, 0);
        }
        #pragma unroll
        for (int r = 0; r < 4; r++) {
            const int p = mt*16 + quad*4 + r;
            const bool pok = (p < nv);
            const int2 md = meta[pok ? p : 0];       // clamped: safe mb
            const int mb = md.x;
            const unsigned cpv = (unsigned)md.y;
            if (pok) {
                if (jok0) {
                    const unsigned mv = M[mb + lb0.x];
                    if (mv >= 256u) {
                        const float tv = (mv != cpv) ? 1.f : 0.f;
                        const float pv = 1.f / (1.f + __expf(-(a0[r] + bj0)));
                        num  = fmaf(pv, tv, num);
                        denp = fmaf(pv, pv, denp);
                        dent += tv;
                    }
                }
                if (jok1) {
                    const unsigned mv = M[mb + lb1.x];
                    if (mv >= 256u) {
                        const float tv = (mv != cpv) ? 1.f : 0.f;
                        const float pv = 1.f / (1.f + __expf(-(a1[r] + bj1)));
                        num  = fmaf(pv, tv, num);
                        denp = fmaf(pv, pv, denp);
                        dent += tv;
                    }
                }
            }
        }
    }

    // wave reduce, block reduce, spread atomics
    #pragma unroll
    for (int off = 32; off > 0; off >>= 1) {
        num  += __shfl_down(num,  off);
        denp += __shfl_down(denp, off);
        dent += __shfl_down(dent, off);
    }
    if (lane == 0) { red_s[wv][0] = num; red_s[wv][1] = denp; red_s[wv][2] = dent; }
    __syncthreads();
    if (tid == 0) {
        const float n_ = red_s[0][0]+red_s[1][0]+red_s[2][0]+red_s[3][0];
        const float p_ = red_s[0][1]+red_s[1][1]+red_s[2][1]+red_s[3][1];
        const float t_ = red_s[0][2]+red_s[1][2]+red_s[2][2]+red_s[3][2];
        const int slot = (blockIdx.x + blockIdx.y*57) & 31;
        atomicAdd(&accs[slot*4 + 0], (double)n_);
        atomicAdd(&accs[slot*4 + 1], (double)p_);
        atomicAdd(&accs[slot*4 + 2], (double)t_);
    }
}

__global__ void k_final(const double* __restrict__ accs, float* __restrict__ out) {
    double num = 0.0, den = 0.0;
    for (int s = 0; s < 32; s++) {
        num += accs[s*4 + 0];
        den += accs[s*4 + 1] + accs[s*4 + 2];
    }
    const double d = den > 1e-6 ? den : 1e-6;
    out[0] = (float)(-2.0 * num / d);
}

extern "C" void kernel_launch(void* const* d_in, const int* in_sizes, int n_in,
                              void* d_out, int out_size, void* d_ws, size_t ws_size,
                              hipStream_t stream) {
    const float* target = (const float*)d_in[0];
    const float* pred   = (const float*)d_in[1];
    const float* W1     = (const float*)d_in[2];
    const float* b1     = (const float*)d_in[3];
    const float* W2     = (const float*)d_in[4];
    const float* b2     = (const float*)d_in[5];
    float* out = (float*)d_out;

    char* ws = (char*)d_ws;
    double*         accs = (double*)ws;                       // 32*4 doubles = 1024 B
    int*            cnt  = (int*)(ws + 1024);
    int2*           meta = (int2*)(ws + 1056);                // 10048*8 = 80,384
    unsigned short* hA   = (unsigned short*)(ws + 81472);     // 628*4096*2 = 5,144,576
    unsigned short* W2t  = (unsigned short*)(ws + 5226048);   // 1824*256*2 = 933,888
    int2*           lut  = (int2*)(ws + 6159936);             // 1824*8 = 14,592
    unsigned short* Mx   = (unsigned short*)(ws + 6174528);   // 3,145,728 (end 9,320,256)

    hipMemsetAsync(d_ws, 0, 1056, stream);                    // accs + cnt
    hipLaunchKernelGGL(k_stage, dim3(1808),     dim3(256), 0, stream,
                       W2, b2, target, pred, W1, b1, W2t, lut, Mx, hA, meta, cnt);
    hipLaunchKernelGGL(k_main,  dim3(57, MS_),  dim3(256), 0, stream,
                       hA, W2t, lut, Mx, meta, cnt, accs);
    hipLaunchKernelGGL(k_final, dim3(1), dim3(1), 0, stream, accs, out);
}